// Round 4
// baseline (237.206 us; speedup 1.0000x reference)
//
#include <hip/hip_runtime.h>

using fx4 = __attribute__((ext_vector_type(4))) float;
using ux4 = __attribute__((ext_vector_type(4))) unsigned int;

__device__ __forceinline__ float bf_lo(unsigned int u) {
    return __uint_as_float(u << 16);
}
__device__ __forceinline__ float bf_hi(unsigned int u) {
    return __uint_as_float(u & 0xffff0000u);
}

// H_bf16 = round_bf16(relu(vfeat @ W + b)), vfeat:[n,64], W:[64,64], b:[64]
// Thread owns one output column c; W column held in 64 VGPRs; rows staged in
// LDS, read back as broadcast ds_read_b128.
__global__ __launch_bounds__(256) void lin_relu_kernel(
    const float* __restrict__ vfeat, const float* __restrict__ W,
    const float* __restrict__ b, unsigned short* __restrict__ Hb, int n_nodes)
{
    __shared__ float sv[8][64];

    const int tid = threadIdx.x;     // 256
    const int c   = tid & 63;        // output column (lane)
    const int w   = tid >> 6;        // wave 0..3

    float wreg[64];
    #pragma unroll
    for (int k = 0; k < 64; ++k) wreg[k] = W[k * 64 + c];
    const float bc = b[c];

    const int ntiles = (n_nodes + 7) >> 3;
    for (int tile = blockIdx.x; tile < ntiles; tile += gridDim.x) {
        const int rbase = tile * 8;
        __syncthreads();             // protect sv from previous-iter readers
        {
            const int i0 = tid, i1 = tid + 256;
            const int r0 = rbase + (i0 >> 6);
            const int r1 = rbase + (i1 >> 6);
            if (r0 < n_nodes) sv[i0 >> 6][i0 & 63] = vfeat[r0 * 64 + (i0 & 63)];
            if (r1 < n_nodes) sv[i1 >> 6][i1 & 63] = vfeat[r1 * 64 + (i1 & 63)];
        }
        __syncthreads();
        #pragma unroll
        for (int rr = 0; rr < 2; ++rr) {
            const int rsub = w * 2 + rr;
            const int r    = rbase + rsub;
            if (r < n_nodes) {
                float acc = bc;
                const fx4* svp = (const fx4*)sv[rsub];   // broadcast ds_read_b128
                #pragma unroll
                for (int k4 = 0; k4 < 16; ++k4) {
                    const fx4 v = svp[k4];
                    acc = fmaf(v.x, wreg[k4 * 4 + 0], acc);
                    acc = fmaf(v.y, wreg[k4 * 4 + 1], acc);
                    acc = fmaf(v.z, wreg[k4 * 4 + 2], acc);
                    acc = fmaf(v.w, wreg[k4 * 4 + 3], acc);
                }
                acc = fmaxf(acc, 0.0f);
                // f32 -> bf16 round-to-nearest-even (values finite, >=0)
                const unsigned int u = __float_as_uint(acc);
                Hb[r * 64 + c] = (unsigned short)((u + 0x7fffu + ((u >> 16) & 1u)) >> 16);
            }
        }
    }
}

// out[2][E][64] : out[0][e] = H[src[e]], out[1][e] = H[dst[e]]
// Task = 16B of bf16 H (8 cols) -> 32B of f32 out. 8 tasks per row.
// Per 8-lane group: one random 128B H-row read, 256B contiguous nt store.
__global__ __launch_bounds__(256) void gather_kernel(
    const ux4* __restrict__ H, const int* __restrict__ src,
    const int* __restrict__ dst, fx4* __restrict__ out, int E)
{
    const long total  = (long)2 * E * 8;           // tasks
    const long stride = (long)gridDim.x * blockDim.x;
    long g = (long)blockIdx.x * blockDim.x + threadIdx.x;

    for (; g + 3 * stride < total; g += 4 * stride) {
        long gg[4]; int nd[4]; ux4 hv[4];
        #pragma unroll
        for (int u = 0; u < 4; ++u) {
            gg[u] = g + u * stride;
            const long row = gg[u] >> 3;
            nd[u] = (row < E) ? src[row] : dst[row - E];
        }
        #pragma unroll
        for (int u = 0; u < 4; ++u)
            hv[u] = H[(long)nd[u] * 8 + (gg[u] & 7)];
        #pragma unroll
        for (int u = 0; u < 4; ++u) {
            fx4 a, bq;
            a.x  = bf_lo(hv[u].x); a.y  = bf_hi(hv[u].x);
            a.z  = bf_lo(hv[u].y); a.w  = bf_hi(hv[u].y);
            bq.x = bf_lo(hv[u].z); bq.y = bf_hi(hv[u].z);
            bq.z = bf_lo(hv[u].w); bq.w = bf_hi(hv[u].w);
            __builtin_nontemporal_store(a,  &out[gg[u] * 2]);
            __builtin_nontemporal_store(bq, &out[gg[u] * 2 + 1]);
        }
    }
    for (; g < total; g += stride) {
        const long row = g >> 3;
        const int nd = (row < E) ? src[row] : dst[row - E];
        const ux4 hv = H[(long)nd * 8 + (g & 7)];
        fx4 a, bq;
        a.x  = bf_lo(hv.x); a.y  = bf_hi(hv.x);
        a.z  = bf_lo(hv.y); a.w  = bf_hi(hv.y);
        bq.x = bf_lo(hv.z); bq.y = bf_hi(hv.z);
        bq.z = bf_lo(hv.w); bq.w = bf_hi(hv.w);
        __builtin_nontemporal_store(a,  &out[g * 2]);
        __builtin_nontemporal_store(bq, &out[g * 2 + 1]);
    }
}

extern "C" void kernel_launch(void* const* d_in, const int* in_sizes, int n_in,
                              void* d_out, int out_size, void* d_ws, size_t ws_size,
                              hipStream_t stream) {
    const float* vfeat = (const float*)d_in[0];
    const int*   src   = (const int*)d_in[1];
    const int*   dst   = (const int*)d_in[2];
    const float* W     = (const float*)d_in[3];
    const float* b     = (const float*)d_in[4];
    float* out = (float*)d_out;

    const int n_nodes = in_sizes[0] / 64;   // 50000
    const int E       = in_sizes[1];        // 1000000

    unsigned short* Hb = (unsigned short*)d_ws;   // n_nodes*64*2 = 6.4 MB

    // 1) Hb = bf16(relu(vfeat @ W + b))
    {
        const int ntiles = (n_nodes + 7) >> 3;
        const int grid = ntiles < 2048 ? ntiles : 2048;
        lin_relu_kernel<<<grid, 256, 0, stream>>>(vfeat, W, b, Hb, n_nodes);
    }

    // 2) gather into both output streams (bf16 -> f32 expand)
    gather_kernel<<<4096, 256, 0, stream>>>((const ux4*)Hb, src, dst,
                                            (fx4*)out, E);
}

// Round 5
// 143.393 us; speedup vs baseline: 1.6542x; 1.6542x over previous
//
#include <hip/hip_runtime.h>

using fx4 = __attribute__((ext_vector_type(4))) float;
using ux2 = __attribute__((ext_vector_type(2))) unsigned int;

__device__ __forceinline__ float bf_lo(unsigned int u) {
    return __uint_as_float(u << 16);
}
__device__ __forceinline__ float bf_hi(unsigned int u) {
    return __uint_as_float(u & 0xffff0000u);
}

// H_bf16 = round_bf16(relu(vfeat @ W + b)), vfeat:[n,64], W:[64,64], b:[64]
__global__ __launch_bounds__(256) void lin_relu_kernel(
    const float* __restrict__ vfeat, const float* __restrict__ W,
    const float* __restrict__ b, unsigned short* __restrict__ Hb, int n_nodes)
{
    __shared__ float sv[8][64];

    const int tid = threadIdx.x;     // 256
    const int c   = tid & 63;        // output column (lane)
    const int w   = tid >> 6;        // wave 0..3

    float wreg[64];
    #pragma unroll
    for (int k = 0; k < 64; ++k) wreg[k] = W[k * 64 + c];
    const float bc = b[c];

    const int ntiles = (n_nodes + 7) >> 3;
    for (int tile = blockIdx.x; tile < ntiles; tile += gridDim.x) {
        const int rbase = tile * 8;
        __syncthreads();             // protect sv from previous-iter readers
        {
            const int i0 = tid, i1 = tid + 256;
            const int r0 = rbase + (i0 >> 6);
            const int r1 = rbase + (i1 >> 6);
            if (r0 < n_nodes) sv[i0 >> 6][i0 & 63] = vfeat[r0 * 64 + (i0 & 63)];
            if (r1 < n_nodes) sv[i1 >> 6][i1 & 63] = vfeat[r1 * 64 + (i1 & 63)];
        }
        __syncthreads();
        #pragma unroll
        for (int rr = 0; rr < 2; ++rr) {
            const int rsub = w * 2 + rr;
            const int r    = rbase + rsub;
            if (r < n_nodes) {
                float acc = bc;
                const fx4* svp = (const fx4*)sv[rsub];   // broadcast ds_read_b128
                #pragma unroll
                for (int k4 = 0; k4 < 16; ++k4) {
                    const fx4 v = svp[k4];
                    acc = fmaf(v.x, wreg[k4 * 4 + 0], acc);
                    acc = fmaf(v.y, wreg[k4 * 4 + 1], acc);
                    acc = fmaf(v.z, wreg[k4 * 4 + 2], acc);
                    acc = fmaf(v.w, wreg[k4 * 4 + 3], acc);
                }
                acc = fmaxf(acc, 0.0f);
                // f32 -> bf16 round-to-nearest-even (finite, >=0)
                const unsigned int u = __float_as_uint(acc);
                Hb[r * 64 + c] = (unsigned short)((u + 0x7fffu + ((u >> 16) & 1u)) >> 16);
            }
        }
    }
}

// out[2][E][64] f32 : out[0][e] = H[src[e]], out[1][e] = H[dst[e]]
// Task = one fx4 of output (4 cols). Thread loads 8B of bf16 (ux2), expands,
// stores one fx4 -> both load and store lane-contiguous. 16 tasks per row.
__global__ __launch_bounds__(256) void gather_kernel(
    const ux2* __restrict__ H, const int* __restrict__ src,
    const int* __restrict__ dst, fx4* __restrict__ out, int E)
{
    const long total  = (long)2 * E * 16;          // fx4 tasks
    const long stride = (long)gridDim.x * blockDim.x;
    long g = (long)blockIdx.x * blockDim.x + threadIdx.x;

    for (; g + 3 * stride < total; g += 4 * stride) {
        int nd[4]; ux2 hv[4];
        #pragma unroll
        for (int u = 0; u < 4; ++u) {
            const long row = (g + u * stride) >> 4;
            nd[u] = (row < E) ? src[row] : dst[row - E];
        }
        #pragma unroll
        for (int u = 0; u < 4; ++u)
            hv[u] = H[(long)nd[u] * 16 + ((g + u * stride) & 15)];
        #pragma unroll
        for (int u = 0; u < 4; ++u) {
            fx4 v;
            v.x = bf_lo(hv[u].x); v.y = bf_hi(hv[u].x);
            v.z = bf_lo(hv[u].y); v.w = bf_hi(hv[u].y);
            __builtin_nontemporal_store(v, &out[g + u * stride]);
        }
    }
    for (; g < total; g += stride) {
        const long row = g >> 4;
        const int nd = (row < E) ? src[row] : dst[row - E];
        const ux2 hv = H[(long)nd * 16 + (g & 15)];
        fx4 v;
        v.x = bf_lo(hv.x); v.y = bf_hi(hv.x);
        v.z = bf_lo(hv.y); v.w = bf_hi(hv.y);
        __builtin_nontemporal_store(v, &out[g]);
    }
}

extern "C" void kernel_launch(void* const* d_in, const int* in_sizes, int n_in,
                              void* d_out, int out_size, void* d_ws, size_t ws_size,
                              hipStream_t stream) {
    const float* vfeat = (const float*)d_in[0];
    const int*   src   = (const int*)d_in[1];
    const int*   dst   = (const int*)d_in[2];
    const float* W     = (const float*)d_in[3];
    const float* b     = (const float*)d_in[4];
    float* out = (float*)d_out;

    const int n_nodes = in_sizes[0] / 64;   // 50000
    const int E       = in_sizes[1];        // 1000000

    unsigned short* Hb = (unsigned short*)d_ws;   // n_nodes*64*2 = 6.4 MB

    // 1) Hb = bf16(relu(vfeat @ W + b))
    {
        const int ntiles = (n_nodes + 7) >> 3;
        const int grid = ntiles < 2048 ? ntiles : 2048;
        lin_relu_kernel<<<grid, 256, 0, stream>>>(vfeat, W, b, Hb, n_nodes);
    }

    // 2) gather into both output streams (bf16 -> f32 expand)
    gather_kernel<<<4096, 256, 0, stream>>>((const ux2*)Hb, src, dst,
                                            (fx4*)out, E);
}

// Round 6
// 117.787 us; speedup vs baseline: 2.0139x; 1.2174x over previous
//
#include <hip/hip_runtime.h>

using fx4 = __attribute__((ext_vector_type(4))) float;
using ux2 = __attribute__((ext_vector_type(2))) unsigned int;

__device__ __forceinline__ float bf_lo(unsigned int u) {
    return __uint_as_float(u << 16);
}
__device__ __forceinline__ float bf_hi(unsigned int u) {
    return __uint_as_float(u & 0xffff0000u);
}

// H_bf16 = round_bf16(relu(vfeat @ W + b)), vfeat:[n,64], W:[64,64], b:[64]
__global__ __launch_bounds__(256) void lin_relu_kernel(
    const float* __restrict__ vfeat, const float* __restrict__ W,
    const float* __restrict__ b, unsigned short* __restrict__ Hb, int n_nodes)
{
    __shared__ float sv[8][64];

    const int tid = threadIdx.x;     // 256
    const int c   = tid & 63;        // output column (lane)
    const int w   = tid >> 6;        // wave 0..3

    float wreg[64];
    #pragma unroll
    for (int k = 0; k < 64; ++k) wreg[k] = W[k * 64 + c];
    const float bc = b[c];

    const int ntiles = (n_nodes + 7) >> 3;
    for (int tile = blockIdx.x; tile < ntiles; tile += gridDim.x) {
        const int rbase = tile * 8;
        __syncthreads();             // protect sv from previous-iter readers
        {
            const int i0 = tid, i1 = tid + 256;
            const int r0 = rbase + (i0 >> 6);
            const int r1 = rbase + (i1 >> 6);
            if (r0 < n_nodes) sv[i0 >> 6][i0 & 63] = vfeat[r0 * 64 + (i0 & 63)];
            if (r1 < n_nodes) sv[i1 >> 6][i1 & 63] = vfeat[r1 * 64 + (i1 & 63)];
        }
        __syncthreads();
        #pragma unroll
        for (int rr = 0; rr < 2; ++rr) {
            const int rsub = w * 2 + rr;
            const int r    = rbase + rsub;
            if (r < n_nodes) {
                float acc = bc;
                const fx4* svp = (const fx4*)sv[rsub];   // broadcast ds_read_b128
                #pragma unroll
                for (int k4 = 0; k4 < 16; ++k4) {
                    const fx4 v = svp[k4];
                    acc = fmaf(v.x, wreg[k4 * 4 + 0], acc);
                    acc = fmaf(v.y, wreg[k4 * 4 + 1], acc);
                    acc = fmaf(v.z, wreg[k4 * 4 + 2], acc);
                    acc = fmaf(v.w, wreg[k4 * 4 + 3], acc);
                }
                acc = fmaxf(acc, 0.0f);
                // f32 -> bf16 round-to-nearest-even (finite, >=0)
                const unsigned int u = __float_as_uint(acc);
                Hb[r * 64 + c] = (unsigned short)((u + 0x7fffu + ((u >> 16) & 1u)) >> 16);
            }
        }
    }
}

// out[2][E][64] f32 : out[0][e] = H[src[e]], out[1][e] = H[dst[e]]
// Block owns 8192 tasks (= 512 output rows). Phase 1: stage 512 idx in LDS.
// Phase 2: issue all 32 H loads per thread (no deps). Phase 3: 32 nt stores.
// Task = one fx4 of output; 16 threads cover one row (load 8B bf16 each).
__global__ __launch_bounds__(256) void gather_kernel(
    const ux2* __restrict__ H, const int* __restrict__ src,
    const int* __restrict__ dst, fx4* __restrict__ out, int E)
{
    __shared__ int sidx[512];
    const long total   = (long)2 * E * 16;          // fx4 tasks
    const int  tid     = threadIdx.x;
    const long base    = (long)blockIdx.x * 8192;   // first task of block
    const int  rowbase = blockIdx.x * 512;          // first output row of block

    // Phase 1: stage this block's 512 row indices (coalesced, 2 per thread)
    #pragma unroll
    for (int i = 0; i < 2; ++i) {
        const int t = tid + i * 256;
        const int r = rowbase + t;
        int v = 0;
        if (r < E)          v = src[r];
        else if (r < 2 * E) v = dst[r - E];
        sidx[t] = v;
    }
    __syncthreads();

    // Phase 2: all 32 independent H loads (32-deep MLP per thread)
    ux2 hv[32];
    #pragma unroll
    for (int k = 0; k < 32; ++k) {
        const int  lt = k * 256 + tid;              // local task 0..8191
        const long g  = base + lt;
        if (g < total) {
            const int nd = sidx[lt >> 4];
            hv[k] = H[(long)nd * 16 + (lt & 15)];
        }
    }

    // Phase 3: all 32 nt stores (1 KB contiguous per wave per store)
    #pragma unroll
    for (int k = 0; k < 32; ++k) {
        const long g = base + (long)k * 256 + tid;
        if (g < total) {
            fx4 v;
            v.x = bf_lo(hv[k].x); v.y = bf_hi(hv[k].x);
            v.z = bf_lo(hv[k].y); v.w = bf_hi(hv[k].y);
            __builtin_nontemporal_store(v, &out[g]);
        }
    }
}

extern "C" void kernel_launch(void* const* d_in, const int* in_sizes, int n_in,
                              void* d_out, int out_size, void* d_ws, size_t ws_size,
                              hipStream_t stream) {
    const float* vfeat = (const float*)d_in[0];
    const int*   src   = (const int*)d_in[1];
    const int*   dst   = (const int*)d_in[2];
    const float* W     = (const float*)d_in[3];
    const float* b     = (const float*)d_in[4];
    float* out = (float*)d_out;

    const int n_nodes = in_sizes[0] / 64;   // 50000
    const int E       = in_sizes[1];        // 1000000

    unsigned short* Hb = (unsigned short*)d_ws;   // n_nodes*64*2 = 6.4 MB

    // 1) Hb = bf16(relu(vfeat @ W + b))
    {
        const int ntiles = (n_nodes + 7) >> 3;
        const int grid = ntiles < 2048 ? ntiles : 2048;
        lin_relu_kernel<<<grid, 256, 0, stream>>>(vfeat, W, b, Hb, n_nodes);
    }

    // 2) gather into both output streams (bf16 -> f32 expand)
    {
        const long total = (long)2 * E * 16;
        const int  nblk  = (int)((total + 8191) / 8192);   // 3907 for E=1e6
        gather_kernel<<<nblk, 256, 0, stream>>>((const ux2*)Hb, src, dst,
                                                (fx4*)out, E);
    }
}

// Round 7
// 115.540 us; speedup vs baseline: 2.0530x; 1.0195x over previous
//
#include <hip/hip_runtime.h>

using fx4 = __attribute__((ext_vector_type(4))) float;
using ux2 = __attribute__((ext_vector_type(2))) unsigned int;

__device__ __forceinline__ float bf_lo(unsigned int u) {
    return __uint_as_float(u << 16);
}
__device__ __forceinline__ float bf_hi(unsigned int u) {
    return __uint_as_float(u & 0xffff0000u);
}

// H_bf16 = round_bf16(relu(vfeat @ W + b)), vfeat:[n,64], W:[64,64], b:[64]
__global__ __launch_bounds__(256) void lin_relu_kernel(
    const float* __restrict__ vfeat, const float* __restrict__ W,
    const float* __restrict__ b, unsigned short* __restrict__ Hb, int n_nodes)
{
    __shared__ float sv[8][64];

    const int tid = threadIdx.x;     // 256
    const int c   = tid & 63;        // output column (lane)
    const int w   = tid >> 6;        // wave 0..3

    float wreg[64];
    #pragma unroll
    for (int k = 0; k < 64; ++k) wreg[k] = W[k * 64 + c];
    const float bc = b[c];

    const int ntiles = (n_nodes + 7) >> 3;
    for (int tile = blockIdx.x; tile < ntiles; tile += gridDim.x) {
        const int rbase = tile * 8;
        __syncthreads();             // protect sv from previous-iter readers
        {
            const int i0 = tid, i1 = tid + 256;
            const int r0 = rbase + (i0 >> 6);
            const int r1 = rbase + (i1 >> 6);
            if (r0 < n_nodes) sv[i0 >> 6][i0 & 63] = vfeat[r0 * 64 + (i0 & 63)];
            if (r1 < n_nodes) sv[i1 >> 6][i1 & 63] = vfeat[r1 * 64 + (i1 & 63)];
        }
        __syncthreads();
        #pragma unroll
        for (int rr = 0; rr < 2; ++rr) {
            const int rsub = w * 2 + rr;
            const int r    = rbase + rsub;
            if (r < n_nodes) {
                float acc = bc;
                const fx4* svp = (const fx4*)sv[rsub];   // broadcast ds_read_b128
                #pragma unroll
                for (int k4 = 0; k4 < 16; ++k4) {
                    const fx4 v = svp[k4];
                    acc = fmaf(v.x, wreg[k4 * 4 + 0], acc);
                    acc = fmaf(v.y, wreg[k4 * 4 + 1], acc);
                    acc = fmaf(v.z, wreg[k4 * 4 + 2], acc);
                    acc = fmaf(v.w, wreg[k4 * 4 + 3], acc);
                }
                acc = fmaxf(acc, 0.0f);
                // f32 -> bf16 round-to-nearest-even (finite, >=0)
                const unsigned int u = __float_as_uint(acc);
                Hb[r * 64 + c] = (unsigned short)((u + 0x7fffu + ((u >> 16) & 1u)) >> 16);
            }
        }
    }
}

// out[2][E][64] f32 : out[0][e] = H[src[e]], out[1][e] = H[dst[e]]
// Block owns 4096 fx4-tasks (= 256 output rows). Phase 1: stage 256 pre-scaled
// node offsets in LDS. Phase 2: 16 independent H loads/thread. Phase 3: 16 nt
// stores. All-int32 task math; block-uniform tail branch.
__global__ __launch_bounds__(256) void gather_kernel(
    const ux2* __restrict__ H, const int* __restrict__ src,
    const int* __restrict__ dst, fx4* __restrict__ out, int E)
{
    __shared__ int soff[256];                       // node*16 element offsets
    const int tid = threadIdx.x;
    const unsigned base  = (unsigned)blockIdx.x * 4096u;   // first task
    const unsigned total = (unsigned)E * 32u;               // 2*E*16 tasks

    // Phase 1: one row index per thread (coalesced), pre-scaled to ux2 units
    {
        const int r = (int)(base >> 4) + tid;
        int v = 0;
        if (r < E)          v = src[r];
        else if (r < 2 * E) v = dst[r - E];
        soff[tid] = v * 16;
    }
    __syncthreads();

    ux2 hv[16];
    if (base + 4096u <= total) {                    // full block (all but last)
        #pragma unroll
        for (int k = 0; k < 16; ++k) {
            const int lt = k * 256 + tid;           // local task 0..4095
            hv[k] = H[soff[lt >> 4] + (lt & 15)];   // 16-deep independent MLP
        }
        #pragma unroll
        for (int k = 0; k < 16; ++k) {
            fx4 v;
            v.x = bf_lo(hv[k].x); v.y = bf_hi(hv[k].x);
            v.z = bf_lo(hv[k].y); v.w = bf_hi(hv[k].y);
            __builtin_nontemporal_store(v, &out[base + (unsigned)(k * 256 + tid)]);
        }
    } else {                                        // tail block
        #pragma unroll
        for (int k = 0; k < 16; ++k) {
            const int lt = k * 256 + tid;
            if (base + (unsigned)lt < total)
                hv[k] = H[soff[lt >> 4] + (lt & 15)];
        }
        #pragma unroll
        for (int k = 0; k < 16; ++k) {
            const unsigned g = base + (unsigned)(k * 256 + tid);
            if (g < total) {
                fx4 v;
                v.x = bf_lo(hv[k].x); v.y = bf_hi(hv[k].x);
                v.z = bf_lo(hv[k].y); v.w = bf_hi(hv[k].y);
                __builtin_nontemporal_store(v, &out[g]);
            }
        }
    }
}

extern "C" void kernel_launch(void* const* d_in, const int* in_sizes, int n_in,
                              void* d_out, int out_size, void* d_ws, size_t ws_size,
                              hipStream_t stream) {
    const float* vfeat = (const float*)d_in[0];
    const int*   src   = (const int*)d_in[1];
    const int*   dst   = (const int*)d_in[2];
    const float* W     = (const float*)d_in[3];
    const float* b     = (const float*)d_in[4];
    float* out = (float*)d_out;

    const int n_nodes = in_sizes[0] / 64;   // 50000
    const int E       = in_sizes[1];        // 1000000

    unsigned short* Hb = (unsigned short*)d_ws;   // n_nodes*64*2 = 6.4 MB

    // 1) Hb = bf16(relu(vfeat @ W + b))
    {
        const int ntiles = (n_nodes + 7) >> 3;
        const int grid = ntiles < 1024 ? ntiles : 1024;  // amortize W regs over ~6 tiles
        lin_relu_kernel<<<grid, 256, 0, stream>>>(vfeat, W, b, Hb, n_nodes);
    }

    // 2) gather into both output streams (bf16 -> f32 expand)
    {
        const long total = (long)2 * E * 16;
        const int  nblk  = (int)((total + 4095) / 4096);   // 7813 for E=1e6
        gather_kernel<<<nblk, 256, 0, stream>>>((const ux2*)Hb, src, dst,
                                                (fx4*)out, E);
    }
}